// Round 1
// baseline (88.759 us; speedup 1.0000x reference)
//
#include <hip/hip_runtime.h>
#include <math.h>

#define H 512
#define W 512
#define PH 256   // maxpool output dims (stride 2, k 3, pad 1)
#define PW 256
#define OH 128   // unfold output dims (stride 4, k 5, pad 1)
#define OW 128
#define NPLANES 96            // 32 * 3
#define BLOCKS_PER_PLANE 8    // for gate partial reduction

// Kernel A: per-plane partial sums of the maxpool(3x3,s2,p1) outputs.
// 96 planes * 8 blocks; each block handles 32 pooled rows (8192 outputs).
__global__ __launch_bounds__(256) void gate_partial_kernel(
    const float* __restrict__ x, float* __restrict__ partials) {
    const int bx = blockIdx.x;
    const int plane = bx / BLOCKS_PER_PLANE;
    const int sub = bx % BLOCKS_PER_PLANE;
    const float* __restrict__ p = x + (size_t)plane * H * W;

    float acc = 0.f;
    const int rows_per_block = PH / BLOCKS_PER_PLANE;  // 32
    for (int i = threadIdx.x; i < rows_per_block * PW; i += 256) {
        const int oh = sub * rows_per_block + (i / PW);
        const int ow = i % PW;
        const int r0 = 2 * oh - 1;
        const int c0 = 2 * ow - 1;
        float m = -INFINITY;
        #pragma unroll
        for (int dr = 0; dr < 3; ++dr) {
            const int r = r0 + dr;
            if ((unsigned)r >= (unsigned)H) continue;
            #pragma unroll
            for (int dc = 0; dc < 3; ++dc) {
                const int c = c0 + dc;
                if ((unsigned)c >= (unsigned)W) continue;
                m = fmaxf(m, p[r * W + c]);
            }
        }
        acc += m;
    }

    // wave64 reduce, then cross-wave via LDS
    #pragma unroll
    for (int off = 32; off > 0; off >>= 1)
        acc += __shfl_down(acc, off, 64);
    __shared__ float smem[4];
    const int lane = threadIdx.x & 63;
    const int wid = threadIdx.x >> 6;
    if (lane == 0) smem[wid] = acc;
    __syncthreads();
    if (threadIdx.x == 0) {
        partials[plane * BLOCKS_PER_PLANE + sub] =
            smem[0] + smem[1] + smem[2] + smem[3];
    }
}

// Kernel B: out = (5x5 window-sum / 25) * silu(mean of pooled)
// 96 planes * 64 blocks; each thread produces one output pixel.
__global__ __launch_bounds__(256) void out_kernel(
    const float* __restrict__ x, const float* __restrict__ partials,
    float* __restrict__ out) {
    const int bx = blockIdx.x;
    const int plane = bx / 64;
    const int chunk = bx % 64;
    const float* __restrict__ p = x + (size_t)plane * H * W;

    // gate (same value for the whole plane; 8 cached loads)
    float s = 0.f;
    #pragma unroll
    for (int i = 0; i < BLOCKS_PER_PLANE; ++i)
        s += partials[plane * BLOCKS_PER_PLANE + i];
    s *= (1.0f / (float)(PH * PW));
    const float gate = s / (1.0f + expf(-s));
    const float scale = gate * (1.0f / 25.0f);

    const int idx = chunk * 256 + threadIdx.x;   // 0..16383
    const int oh = idx / OW;
    const int ow = idx % OW;
    const int r0 = 4 * oh - 1;
    const int c0 = 4 * ow - 1;

    float acc = 0.f;
    #pragma unroll
    for (int dr = 0; dr < 5; ++dr) {
        const int r = r0 + dr;
        if ((unsigned)r >= (unsigned)H) continue;
        #pragma unroll
        for (int dc = 0; dc < 5; ++dc) {
            const int c = c0 + dc;
            if ((unsigned)c >= (unsigned)W) continue;
            acc += p[r * W + c];
        }
    }
    out[(size_t)plane * (OH * OW) + idx] = acc * scale;
}

extern "C" void kernel_launch(void* const* d_in, const int* in_sizes, int n_in,
                              void* d_out, int out_size, void* d_ws, size_t ws_size,
                              hipStream_t stream) {
    const float* x = (const float*)d_in[0];
    float* out = (float*)d_out;
    float* partials = (float*)d_ws;   // 768 floats

    gate_partial_kernel<<<NPLANES * BLOCKS_PER_PLANE, 256, 0, stream>>>(x, partials);
    out_kernel<<<NPLANES * 64, 256, 0, stream>>>(x, partials, out);
}

// Round 2
// 40.655 us; speedup vs baseline: 2.1832x; 2.1832x over previous
//
#include <hip/hip_runtime.h>
#include <math.h>

#define H 512
#define W 512
#define PH 256   // maxpool output dims (k3, s2, p1)
#define PW 256
#define OH 128   // unfold output dims (k5, s4, p1)
#define OW 128
#define NPLANES 96         // 32 * 3
#define GATE_BLOCKS 16     // blocks per plane in gate pass

__device__ __forceinline__ float4 fmax4(float4 a, float4 b) {
    return make_float4(fmaxf(a.x, b.x), fmaxf(a.y, b.y),
                       fmaxf(a.z, b.z), fmaxf(a.w, b.w));
}
__device__ __forceinline__ float4 fadd4(float4 a, float4 b) {
    return make_float4(a.x + b.x, a.y + b.y, a.z + b.z, a.w + b.w);
}

// Kernel A: per-plane partial sums of maxpool(3x3,s2,p1) outputs.
// 96 planes * 16 blocks; block = 4 waves; each wave owns 4 pooled rows.
// Lane l covers pooled cols 4l..4l+3 via input cols 8l..8l+7 (2 x float4,
// fully coalesced: 64 lanes = one full 512-col row). 9 shared input rows
// per wave, all loads independent. -inf padding via clamp-duplicate trick
// (row/col -1 clamped into bounds is a duplicate, harmless under max).
__global__ __launch_bounds__(256, 4) void gate_partial_kernel(
    const float* __restrict__ x, float* __restrict__ partials) {
    const int bx = blockIdx.x;
    const int plane = bx / GATE_BLOCKS;
    const int sub = bx % GATE_BLOCKS;
    const float* __restrict__ p = x + (size_t)plane * (H * W);
    const int wid = threadIdx.x >> 6;
    const int lane = threadIdx.x & 63;
    const int oh0 = sub * 16 + wid * 4;   // first pooled row of this wave
    const int col = lane << 3;

    float4 a[9], b[9];
    #pragma unroll
    for (int j = 0; j < 9; ++j) {
        int r = 2 * oh0 - 1 + j;
        if (r < 0) r = 0;                 // duplicate row 0: max-safe
        const float* rp = p + r * W + col;
        a[j] = *(const float4*)(rp);
        b[j] = *(const float4*)(rp + 4);
    }

    float acc = 0.f;
    #pragma unroll
    for (int k = 0; k < 4; ++k) {
        // vertical max over input rows 2k, 2k+1, 2k+2 (pooled row oh0+k)
        float4 va = fmax4(fmax4(a[2 * k], a[2 * k + 1]), a[2 * k + 2]);
        float4 vb = fmax4(fmax4(b[2 * k], b[2 * k + 1]), b[2 * k + 2]);
        // horizontal: v[-1] from left lane's v7; lane 0 duplicates v0
        float vL = __shfl_up(vb.w, 1, 64);
        if (lane == 0) vL = va.x;
        acc += fmaxf(fmaxf(vL, va.x), va.y);     // ow = 4l
        acc += fmaxf(fmaxf(va.y, va.z), va.w);   // ow = 4l+1
        acc += fmaxf(fmaxf(va.w, vb.x), vb.y);   // ow = 4l+2
        acc += fmaxf(fmaxf(vb.y, vb.z), vb.w);   // ow = 4l+3
    }

    // wave64 reduce, then cross-wave via LDS
    #pragma unroll
    for (int off = 32; off > 0; off >>= 1)
        acc += __shfl_down(acc, off, 64);
    __shared__ float smem[4];
    if (lane == 0) smem[wid] = acc;
    __syncthreads();
    if (threadIdx.x == 0) {
        partials[plane * GATE_BLOCKS + sub] =
            smem[0] + smem[1] + smem[2] + smem[3];
    }
}

// Kernel B: out = (5x5 s4 p1 window-sum / 25) * silu(mean of pooled).
// 96 planes * 32 blocks; block = 4 waves; wave owns one output row.
// Lane l produces outputs ow=2l,2l+1 from input cols 8l..8l+7 (+shfl for
// col-1). Zero padding: OOB rows skipped, lane-0 left col = 0.
__global__ __launch_bounds__(256) void out_kernel(
    const float* __restrict__ x, const float* __restrict__ partials,
    float* __restrict__ out) {
    const int bx = blockIdx.x;
    const int plane = bx >> 5;
    const int sub = bx & 31;
    const float* __restrict__ p = x + (size_t)plane * (H * W);

    float s = 0.f;
    #pragma unroll
    for (int i = 0; i < GATE_BLOCKS; ++i)
        s += partials[plane * GATE_BLOCKS + i];
    s *= (1.0f / (float)(PH * PW));
    const float gate = s / (1.0f + expf(-s));
    const float scale = gate * (1.0f / 25.0f);

    const int wid = threadIdx.x >> 6;
    const int lane = threadIdx.x & 63;
    const int oh = sub * 4 + wid;         // output row
    const int col = lane << 3;

    float4 sa = make_float4(0.f, 0.f, 0.f, 0.f);
    float4 sb = make_float4(0.f, 0.f, 0.f, 0.f);
    #pragma unroll
    for (int j = 0; j < 5; ++j) {
        const int r = 4 * oh - 1 + j;
        if ((unsigned)r < (unsigned)H) {  // zero pad: skip OOB rows
            const float* rp = p + r * W + col;
            sa = fadd4(sa, *(const float4*)(rp));
            sb = fadd4(sb, *(const float4*)(rp + 4));
        }
    }
    float sL = __shfl_up(sb.w, 1, 64);
    if (lane == 0) sL = 0.f;              // zero pad at col -1
    const float o0 = (sL + sa.x + sa.y + sa.z + sa.w) * scale;   // ow=2l
    const float o1 = (sa.w + sb.x + sb.y + sb.z + sb.w) * scale; // ow=2l+1

    float* orow = out + (size_t)plane * (OH * OW) + (size_t)oh * OW;
    *(float2*)&orow[2 * lane] = make_float2(o0, o1);
}

extern "C" void kernel_launch(void* const* d_in, const int* in_sizes, int n_in,
                              void* d_out, int out_size, void* d_ws, size_t ws_size,
                              hipStream_t stream) {
    const float* x = (const float*)d_in[0];
    float* out = (float*)d_out;
    float* partials = (float*)d_ws;   // 96*16 = 1536 floats

    gate_partial_kernel<<<NPLANES * GATE_BLOCKS, 256, 0, stream>>>(x, partials);
    out_kernel<<<NPLANES * 32, 256, 0, stream>>>(x, partials, out);
}

// Round 3
// 26.170 us; speedup vs baseline: 3.3916x; 1.5535x over previous
//
#include <hip/hip_runtime.h>
#include <math.h>

#define H 512
#define W 512
#define PH 256   // maxpool output dims (k3, s2, p1)
#define PW 256
#define OH 128   // unfold output dims (k5, s4, p1)
#define OW 128
#define NPLANES 96          // 32 * 3
#define TILES_PER_PLANE 16  // blocks per plane; each block = 4 waves = 4 t-tiles
#define WS_PARTIALS 0       // float offset of partials in d_ws
#define WS_WSUM 2048        // float offset of window sums in d_ws

__device__ __forceinline__ float4 fmax4(float4 a, float4 b) {
    return make_float4(fmaxf(a.x, b.x), fmaxf(a.y, b.y),
                       fmaxf(a.z, b.z), fmaxf(a.w, b.w));
}
__device__ __forceinline__ float4 fadd4(float4 a, float4 b) {
    return make_float4(a.x + b.x, a.y + b.y, a.z + b.z, a.w + b.w);
}
__device__ __forceinline__ float hsum4(float4 a) {
    return a.x + a.y + a.z + a.w;
}

// Fused pass: one read of x produces BOTH
//  (a) per-block partial sums of maxpool(3x3,s2,p1) outputs  -> ws partials
//  (b) unscaled 5x5/s4/p1 window sums                        -> ws wsum
// Wave t owns input rows 8t-1..8t+7 (9 rows):
//   pooled rows 4t..4t+3   (rows 2ph-1..2ph+1 each)
//   output rows 2t, 2t+1   (rows 8t-1..8t+3 and 8t+3..8t+7)
// Lane l holds cols 8l..8l+7 as 2 x float4 (64 lanes = full 512-col row).
__global__ __launch_bounds__(256, 4) void fused_kernel(
    const float* __restrict__ x, float* __restrict__ ws) {
    const int bx = blockIdx.x;
    const int plane = bx / TILES_PER_PLANE;
    const int sub = bx % TILES_PER_PLANE;
    const float* __restrict__ p = x + (size_t)plane * (H * W);
    const int wid = threadIdx.x >> 6;
    const int lane = threadIdx.x & 63;
    const int t = sub * 4 + wid;          // 0..63: tile of 8 input rows
    const int col = lane << 3;

    // load 9 rows; row -1 clamped to 0 (max-safe duplicate; zeroed for sum)
    float4 a[9], b[9];
    #pragma unroll
    for (int j = 0; j < 9; ++j) {
        int r = 8 * t - 1 + j;
        if (r < 0) r = 0;
        const float* rp = p + r * W + col;
        a[j] = *(const float4*)(rp);
        b[j] = *(const float4*)(rp + 4);
    }

    // ---- maxpool partial sum (pooled rows 4t..4t+3) ----
    float acc = 0.f;
    #pragma unroll
    for (int k = 0; k < 4; ++k) {
        float4 va = fmax4(fmax4(a[2 * k], a[2 * k + 1]), a[2 * k + 2]);
        float4 vb = fmax4(fmax4(b[2 * k], b[2 * k + 1]), b[2 * k + 2]);
        float vL = __shfl_up(vb.w, 1, 64);
        if (lane == 0) vL = va.x;          // duplicate: max-safe
        acc += fmaxf(fmaxf(vL, va.x), va.y);
        acc += fmaxf(fmaxf(va.y, va.z), va.w);
        acc += fmaxf(fmaxf(va.w, vb.x), vb.y);
        acc += fmaxf(fmaxf(vb.y, vb.z), vb.w);
    }
    #pragma unroll
    for (int off = 32; off > 0; off >>= 1)
        acc += __shfl_down(acc, off, 64);
    __shared__ float smem[4];
    if (lane == 0) smem[wid] = acc;

    // ---- 5x5 window sums (output rows 2t, 2t+1) ----
    // row 8t-1 (j=0) is the zero-pad row when t==0
    float4 z = make_float4(0.f, 0.f, 0.f, 0.f);
    float4 a0 = (t == 0) ? z : a[0];
    float4 b0 = (t == 0) ? z : b[0];
    float4 sa0 = fadd4(fadd4(fadd4(a0, a[1]), fadd4(a[2], a[3])), a[4]);
    float4 sb0 = fadd4(fadd4(fadd4(b0, b[1]), fadd4(b[2], b[3])), b[4]);
    float4 sa1 = fadd4(fadd4(fadd4(a[4], a[5]), fadd4(a[6], a[7])), a[8]);
    float4 sb1 = fadd4(fadd4(fadd4(b[4], b[5]), fadd4(b[6], b[7])), b[8]);

    float* wrow = ws + WS_WSUM + (size_t)plane * (OH * OW);
    {
        float sL = __shfl_up(sb0.w, 1, 64);
        if (lane == 0) sL = 0.f;           // zero pad at col -1
        float o0 = sL + hsum4(sa0);        // ow = 2l
        float o1 = sa0.w + hsum4(sb0);     // ow = 2l+1
        *(float2*)&wrow[(2 * t) * OW + 2 * lane] = make_float2(o0, o1);
    }
    {
        float sL = __shfl_up(sb1.w, 1, 64);
        if (lane == 0) sL = 0.f;
        float o0 = sL + hsum4(sa1);
        float o1 = sa1.w + hsum4(sb1);
        *(float2*)&wrow[(2 * t + 1) * OW + 2 * lane] = make_float2(o0, o1);
    }

    __syncthreads();
    if (threadIdx.x == 0) {
        ws[WS_PARTIALS + plane * TILES_PER_PLANE + sub] =
            smem[0] + smem[1] + smem[2] + smem[3];
    }
}

// Scale pass: out = wsum * silu(mean_pooled) / 25.  96 planes * 4 blocks;
// each thread handles 4 float4 (16 outputs).
__global__ __launch_bounds__(256) void scale_kernel(
    const float* __restrict__ ws, float* __restrict__ out) {
    const int bx = blockIdx.x;
    const int plane = bx >> 2;
    const int quarter = bx & 3;

    float s = 0.f;
    #pragma unroll
    for (int i = 0; i < TILES_PER_PLANE; ++i)
        s += ws[WS_PARTIALS + plane * TILES_PER_PLANE + i];
    s *= (1.0f / (float)(PH * PW));
    const float gate = s / (1.0f + expf(-s));
    const float scale = gate * (1.0f / 25.0f);

    const float4* src = (const float4*)(ws + WS_WSUM + (size_t)plane * (OH * OW));
    float4* dst = (float4*)(out + (size_t)plane * (OH * OW));
    const int base = quarter * 1024 + threadIdx.x;   // float4 index
    #pragma unroll
    for (int i = 0; i < 4; ++i) {
        const int idx = base + i * 256;
        float4 v = src[idx];
        dst[idx] = make_float4(v.x * scale, v.y * scale,
                               v.z * scale, v.w * scale);
    }
}

extern "C" void kernel_launch(void* const* d_in, const int* in_sizes, int n_in,
                              void* d_out, int out_size, void* d_ws, size_t ws_size,
                              hipStream_t stream) {
    const float* x = (const float*)d_in[0];
    float* out = (float*)d_out;
    float* ws = (float*)d_ws;

    fused_kernel<<<NPLANES * TILES_PER_PLANE, 256, 0, stream>>>(x, ws);
    scale_kernel<<<NPLANES * 4, 256, 0, stream>>>(ws, out);
}